// Round 1
// baseline (310.650 us; speedup 1.0000x reference)
//
#include <hip/hip_runtime.h>
#include <hip/hip_bf16.h>
#include <stdint.h>

#define E_N   30000
#define C_IN  128
#define C_OUT 256
#define B_N   4
#define KTAP  5
#define BN    64
#define GRIDX 512

typedef short bf16x8 __attribute__((ext_vector_type(8)));
typedef float f32x4  __attribute__((ext_vector_type(4)));

static __device__ __forceinline__ unsigned short f2bf(float f) {
    union { float f; uint32_t u; } v; v.f = f;
    uint32_t r = (v.u + 0x7FFFu + ((v.u >> 16) & 1u)) >> 16;
    return (unsigned short)r;
}
static __device__ __forceinline__ float bf2f(uint32_t h) {
    union { uint32_t u; float f; } v; v.u = h << 16;
    return v.f;
}

// sum and |diff| of two bf16x8 chunks (f32 math, round back to bf16)
static __device__ __forceinline__ void comb8(const uint4& u, const uint4& v,
                                             uint4& s, uint4& d) {
    const uint32_t* a = (const uint32_t*)&u;
    const uint32_t* b = (const uint32_t*)&v;
    uint32_t* so = (uint32_t*)&s;
    uint32_t* dr = (uint32_t*)&d;
#pragma unroll
    for (int i = 0; i < 4; ++i) {
        float x0 = bf2f(a[i] & 0xFFFFu), x1 = bf2f(a[i] >> 16);
        float y0 = bf2f(b[i] & 0xFFFFu), y1 = bf2f(b[i] >> 16);
        so[i] = (uint32_t)f2bf(x0 + y0) | ((uint32_t)f2bf(x1 + y1) << 16);
        dr[i] = (uint32_t)f2bf(fabsf(x0 - y0)) | ((uint32_t)f2bf(fabsf(x1 - y1)) << 16);
    }
}

// ---------------------------------------------------------------------------
// Pack conv_w [256][128][5] f32 -> bf16 A-fragments, K tap-major:
// kappa = tap*128 + c.  A-frag for mfma_f32_16x16x32_bf16:
// lane holds A[m = mt*16 + (lane&15)][k = s*32 + (lane>>4)*8 + j], j=0..7.
// Linear halfword index: ((s*16 + mt)*64 + lane)*8 + j,  s = tap*4 + cbi.
// ---------------------------------------------------------------------------
__global__ void pack_w_kernel(const float* __restrict__ w,
                              unsigned short* __restrict__ wp) {
    int tid = blockIdx.x * blockDim.x + threadIdx.x;   // 20480 threads total
    if (tid >= 20 * 16 * 64) return;
    int s    = tid >> 10;
    int mt   = (tid >> 6) & 15;
    int lane = tid & 63;
    int m    = mt * 16 + (lane & 15);
    int kb   = s * 32 + ((lane >> 4) & 3) * 8;
    uint32_t pv[4];
    for (int jj = 0; jj < 4; ++jj) {
        unsigned short lo, hi;
        {
            int kk = kb + 2 * jj;
            int t = kk >> 7, c = kk & 127;
            lo = f2bf(w[(m * C_IN + c) * KTAP + t]);
        }
        {
            int kk = kb + 2 * jj + 1;
            int t = kk >> 7, c = kk & 127;
            hi = f2bf(w[(m * C_IN + c) * KTAP + t]);
        }
        pv[jj] = (uint32_t)lo | ((uint32_t)hi << 16);
    }
    uint4 val; val.x = pv[0]; val.y = pv[1]; val.z = pv[2]; val.w = pv[3];
    *(uint4*)(wp + (size_t)tid * 8) = val;
}

// ---------------------------------------------------------------------------
// Transpose x [B][C][E] f32 -> xT [B][E][C] bf16 (coalesced gathers in GEMM).
// ---------------------------------------------------------------------------
__global__ void transpose_kernel(const float* __restrict__ x,
                                 unsigned short* __restrict__ xT) {
    __shared__ float ld[C_IN][64 + 1];
    int b  = blockIdx.y;
    int e0 = blockIdx.x * 64;
    int t  = threadIdx.x;
    bool full = (e0 + 64 <= E_N);
    for (int pass = 0; pass < 8; ++pass) {
        int c  = pass * 16 + (t >> 4);
        int eo = (t & 15) * 4;
        if (full) {
            const float4 v = *(const float4*)(x + ((size_t)(b * C_IN + c) * E_N + e0 + eo));
            ld[c][eo] = v.x; ld[c][eo + 1] = v.y; ld[c][eo + 2] = v.z; ld[c][eo + 3] = v.w;
        } else {
            for (int i = 0; i < 4; ++i) {
                int e = e0 + eo + i;
                ld[c][eo + i] = (e < E_N) ? x[(size_t)(b * C_IN + c) * E_N + e] : 0.f;
            }
        }
    }
    __syncthreads();
    for (int pass = 0; pass < 4; ++pass) {
        int el = pass * 16 + (t >> 4);
        int c0 = (t & 15) * 8;
        int e  = e0 + el;
        if (e < E_N) {
            uint32_t pk[4];
            for (int i = 0; i < 4; ++i) {
                unsigned short lo = f2bf(ld[c0 + 2 * i][el]);
                unsigned short hi = f2bf(ld[c0 + 2 * i + 1][el]);
                pk[i] = (uint32_t)lo | ((uint32_t)hi << 16);
            }
            uint4 v; v.x = pk[0]; v.y = pk[1]; v.z = pk[2]; v.w = pk[3];
            *(uint4*)(xT + (size_t)(b * E_N + e) * C_IN + c0) = v;
        }
    }
}

// ---------------------------------------------------------------------------
// Fused gather + tap-combine + GEMM with REGISTER-RESIDENT WEIGHTS.
//
// Each block: batch fixed (bq = blockIdx.x & 3, valid since GRIDX % 4 == 0),
// grid-strides over column chunks q = bid, bid+512, ... (chunk = 64 edges of
// one batch; et = q>>2).  Per wave, taps 0..3 of its two 16-row m-tiles are
// cached in 128 VGPRs ONCE per block and reused for every chunk -- removing
// 32 of the 40 per-chunk L2 weight wave-loads that sat on the s-loop's
// critical path (600 MB -> ~290 MB of L2 weight traffic).  Tap 4 stays as a
// per-chunk load to keep peak VGPR < 256 (no spill).
//
// Pipeline per chunk (single 80 KB LDS buffer, 2 barriers):
//   [gather(q+1) in flight + ne(q+2) in flight] MFMA(q)+stores(q)
//   | barrier | combine+LDS(q+1), issue gather(q+2)  | barrier | ...
// ---------------------------------------------------------------------------
__launch_bounds__(512, 2)
__global__ void mesh_gemm(const unsigned short* __restrict__ wp,
                          const unsigned short* __restrict__ xT,
                          const int* __restrict__ ne,
                          const float* __restrict__ bias,
                          float* __restrict__ out) {
    __shared__ uint4 gbuf[KTAP][BN][16];   // 81,920 B (XOR-swizzled chunks)

    const int tid  = threadIdx.x;
    const int lane = tid & 63;
    const int wave = tid >> 6;
    const int bq   = blockIdx.x & 3;                    // fixed batch per block
    const int NQ   = ((E_N + BN - 1) / BN) * B_N;       // 469*4 = 1876 chunks

    // gather role: 8 threads/edge, each owns chunks ci and ci+8
    const int col = tid >> 3;
    const int ci  = tid & 7;
    const int sw  = col & 15;
    const int cl  = ci ^ sw;
    const int ch  = (ci + 8) ^ sw;

    const unsigned short* xb   = xT  + (size_t)bq * E_N * C_IN;
    const int*            neb  = ne  + (size_t)bq * E_N * 4;
    float*                outb = out + (size_t)bq * C_OUT * E_N;

    // MFMA-role constants
    const uint4* wp16 = (const uint4*)wp;
    const int nl = lane & 15;
    const int kq = lane >> 4;

    // register weight cache: taps 0..3 (s = 0..15), 2 m-tiles/wave = 128 VGPRs
    uint4 wc0[16], wc1[16];
#pragma unroll
    for (int s = 0; s < 16; ++s) {
        wc0[s] = wp16[(s * 16 + wave * 2 + 0) * 64 + lane];
        wc1[s] = wp16[(s * 16 + wave * 2 + 1) * 64 + lane];
    }

    // hoist bias
    float bvl[2][4];
#pragma unroll
    for (int mt = 0; mt < 2; ++mt)
#pragma unroll
        for (int r = 0; r < 4; ++r)
            bvl[mt][r] = bias[(wave * 2 + mt) * 16 + kq * 4 + r];

    auto egOf = [&](int q) {
        int e = (q >> 2) * BN + col;
        return (e < E_N) ? e : (E_N - 1);
    };

    // ---------------- helpers ----------------
    auto gather10 = [&](int eg, const int4& nb, uint4* g) {
        const uint4* r0 = (const uint4*)(xb + (size_t)eg   * C_IN) + ci;
        const uint4* r1 = (const uint4*)(xb + (size_t)nb.x * C_IN) + ci;
        const uint4* r2 = (const uint4*)(xb + (size_t)nb.y * C_IN) + ci;
        const uint4* r3 = (const uint4*)(xb + (size_t)nb.z * C_IN) + ci;
        const uint4* r4 = (const uint4*)(xb + (size_t)nb.w * C_IN) + ci;
        g[0] = r0[0]; g[1] = r1[0]; g[2] = r2[0]; g[3] = r3[0]; g[4] = r4[0];
        g[5] = r0[8]; g[6] = r1[8]; g[7] = r2[8]; g[8] = r3[8]; g[9] = r4[8];
    };
    auto combineStore = [&](uint4* g) {
        uint4 s, d;
        gbuf[0][col][cl] = g[0];
        comb8(g[1], g[3], s, d); gbuf[1][col][cl] = s; gbuf[3][col][cl] = d;
        comb8(g[2], g[4], s, d); gbuf[2][col][cl] = s; gbuf[4][col][cl] = d;
        gbuf[0][col][ch] = g[5];
        comb8(g[6], g[8], s, d); gbuf[1][col][ch] = s; gbuf[3][col][ch] = d;
        comb8(g[7], g[9], s, d); gbuf[2][col][ch] = s; gbuf[4][col][ch] = d;
    };
    auto mfmaStore = [&](int et) {
        f32x4 acc[2][4];
#pragma unroll
        for (int mt = 0; mt < 2; ++mt)
#pragma unroll
            for (int nt = 0; nt < 4; ++nt)
                acc[mt][nt] = (f32x4){0.f, 0.f, 0.f, 0.f};
        // taps 0..3 from register cache (static indexing -- full unroll)
#pragma unroll
        for (int s = 0; s < 16; ++s) {
            const int tap = s >> 2, cbi = s & 3;
            bf16x8 af0 = *(bf16x8*)&wc0[s];
            bf16x8 af1 = *(bf16x8*)&wc1[s];
#pragma unroll
            for (int nt = 0; nt < 4; ++nt) {
                uint4 bv = gbuf[tap][nt * 16 + nl][((cbi << 2) + kq) ^ nl];
                bf16x8 bf = *(bf16x8*)&bv;
                acc[0][nt] = __builtin_amdgcn_mfma_f32_16x16x32_bf16(af0, bf, acc[0][nt], 0, 0, 0);
                acc[1][nt] = __builtin_amdgcn_mfma_f32_16x16x32_bf16(af1, bf, acc[1][nt], 0, 0, 0);
            }
        }
        // tap 4 (s = 16..19): per-chunk L2 loads (keeps peak VGPR < 256)
#pragma unroll
        for (int s = 16; s < 20; ++s) {
            const int cbi = s & 3;
            uint4 w0 = wp16[(s * 16 + wave * 2 + 0) * 64 + lane];
            uint4 w1 = wp16[(s * 16 + wave * 2 + 1) * 64 + lane];
            bf16x8 af0 = *(bf16x8*)&w0;
            bf16x8 af1 = *(bf16x8*)&w1;
#pragma unroll
            for (int nt = 0; nt < 4; ++nt) {
                uint4 bv = gbuf[4][nt * 16 + nl][((cbi << 2) + kq) ^ nl];
                bf16x8 bf = *(bf16x8*)&bv;
                acc[0][nt] = __builtin_amdgcn_mfma_f32_16x16x32_bf16(af0, bf, acc[0][nt], 0, 0, 0);
                acc[1][nt] = __builtin_amdgcn_mfma_f32_16x16x32_bf16(af1, bf, acc[1][nt], 0, 0, 0);
            }
        }
        // epilogue: C/D col = lane&15, row = kq*4 + r
        const int e0 = et * BN;
#pragma unroll
        for (int mt = 0; mt < 2; ++mt) {
            const int ob = (wave * 2 + mt) * 16 + kq * 4;
#pragma unroll
            for (int r = 0; r < 4; ++r) {
                const int o = ob + r;
                const float bv = bvl[mt][r];
#pragma unroll
                for (int nt = 0; nt < 4; ++nt) {
                    const int e = e0 + nt * 16 + nl;
                    if (e < E_N)
                        outb[(size_t)o * E_N + e] = acc[mt][nt][r] + bv;
                }
            }
        }
    };

    // ---------------- pipeline prologue ----------------
    uint4 g[10];
    int q = blockIdx.x;                       // first chunk (always < NQ)
    {
        int eg = egOf(q);
        int4 nb = *(const int4*)(neb + (size_t)eg * 4);
        gather10(eg, nb, g);
    }
    int qg = q + GRIDX;                       // next chunk to gather
    int egN = 0; int4 nbN = {0, 0, 0, 0};
    if (qg < NQ) { egN = egOf(qg); nbN = *(const int4*)(neb + (size_t)egN * 4); }

    combineStore(g);                          // stage chunk q
    if (qg < NQ) {
        gather10(egN, nbN, g);                // gather q+G (in flight over MFMA)
        int qp = qg + GRIDX;
        if (qp < NQ) { egN = egOf(qp); nbN = *(const int4*)(neb + (size_t)egN * 4); }
    }
    __syncthreads();                          // gbuf(q) visible

    // ---------------- main loop ----------------
    for (;;) {
        mfmaStore(q >> 2);                    // compute chunk q (reg weights)
        __syncthreads();                      // gbuf reads done
        const int qc = q + GRIDX;
        if (qc >= NQ) break;
        combineStore(g);                      // stage chunk qc
        const int qg2 = qc + GRIDX;
        if (qg2 < NQ) {
            gather10(egN, nbN, g);            // gather qc+G (in flight)
            const int qp = qg2 + GRIDX;
            if (qp < NQ) { egN = egOf(qp); nbN = *(const int4*)(neb + (size_t)egN * 4); }
        }
        __syncthreads();                      // gbuf(qc) visible
        q = qc;
    }
}

// ---------------------------------------------------------------------------
// Fallback (ws too small): direct fp32 compute, slow but correct.
// ---------------------------------------------------------------------------
__global__ void fallback_kernel(const float* __restrict__ x,
                                const int* __restrict__ ne,
                                const float* __restrict__ w,
                                const float* __restrict__ bias,
                                float* __restrict__ out) {
    size_t id = (size_t)blockIdx.x * blockDim.x + threadIdx.x;
    if (id >= (size_t)B_N * C_OUT * E_N) return;
    int e = (int)(id % E_N);
    int o = (int)((id / E_N) % C_OUT);
    int b = (int)(id / ((size_t)E_N * C_OUT));
    const int4 nb = *(const int4*)(ne + ((size_t)b * E_N + e) * 4);
    float acc = bias[o];
    for (int c = 0; c < C_IN; ++c) {
        const float* xb = x + (size_t)(b * C_IN + c) * E_N;
        float s0 = xb[e];
        float x1 = xb[nb.x], x2 = xb[nb.y], x3 = xb[nb.z], x4 = xb[nb.w];
        const float* wo = w + (size_t)(o * C_IN + c) * KTAP;
        acc += wo[0] * s0
             + wo[1] * (x1 + x3)
             + wo[2] * (x2 + x4)
             + wo[3] * fabsf(x1 - x3)
             + wo[4] * fabsf(x2 - x4);
    }
    out[id] = acc;
}

extern "C" void kernel_launch(void* const* d_in, const int* in_sizes, int n_in,
                              void* d_out, int out_size, void* d_ws, size_t ws_size,
                              hipStream_t stream) {
    const float* x      = (const float*)d_in[0];
    const int*   ne_idx = (const int*)d_in[1];
    const float* conv_w = (const float*)d_in[2];
    const float* conv_b = (const float*)d_in[3];
    float* out = (float*)d_out;

    const size_t xT_off = 512 * 1024;
    const size_t need   = xT_off + (size_t)B_N * E_N * C_IN * 2;  // ~31.2 MB

    if (ws_size < need) {
        size_t total = (size_t)B_N * C_OUT * E_N;
        int blocks = (int)((total + 255) / 256);
        fallback_kernel<<<blocks, 256, 0, stream>>>(x, ne_idx, conv_w, conv_b, out);
        return;
    }

    unsigned short* wp = (unsigned short*)d_ws;
    unsigned short* xT = (unsigned short*)((char*)d_ws + xT_off);

    pack_w_kernel<<<80, 256, 0, stream>>>(conv_w, wp);
    dim3 tg((E_N + 63) / 64, B_N);
    transpose_kernel<<<tg, 256, 0, stream>>>(x, xT);
    mesh_gemm<<<dim3(GRIDX), 512, 0, stream>>>(wp, xT, ne_idx, conv_b, out);
}

// Round 2
// 244.737 us; speedup vs baseline: 1.2693x; 1.2693x over previous
//
#include <hip/hip_runtime.h>
#include <hip/hip_bf16.h>
#include <stdint.h>

#define E_N   30000
#define C_IN  128
#define C_OUT 256
#define B_N   4
#define KTAP  5
#define BN    64

typedef short bf16x8 __attribute__((ext_vector_type(8)));
typedef float f32x4  __attribute__((ext_vector_type(4)));

static __device__ __forceinline__ unsigned short f2bf(float f) {
    union { float f; uint32_t u; } v; v.f = f;
    uint32_t r = (v.u + 0x7FFFu + ((v.u >> 16) & 1u)) >> 16;
    return (unsigned short)r;
}
static __device__ __forceinline__ float bf2f(uint32_t h) {
    union { uint32_t u; float f; } v; v.u = h << 16;
    return v.f;
}

// sum and |diff| of two bf16x8 chunks (f32 math, round back to bf16)
static __device__ __forceinline__ void comb8(const uint4& u, const uint4& v,
                                             uint4& s, uint4& d) {
    const uint32_t* a = (const uint32_t*)&u;
    const uint32_t* b = (const uint32_t*)&v;
    uint32_t* so = (uint32_t*)&s;
    uint32_t* dr = (uint32_t*)&d;
#pragma unroll
    for (int i = 0; i < 4; ++i) {
        float x0 = bf2f(a[i] & 0xFFFFu), x1 = bf2f(a[i] >> 16);
        float y0 = bf2f(b[i] & 0xFFFFu), y1 = bf2f(b[i] >> 16);
        so[i] = (uint32_t)f2bf(x0 + y0) | ((uint32_t)f2bf(x1 + y1) << 16);
        dr[i] = (uint32_t)f2bf(fabsf(x0 - y0)) | ((uint32_t)f2bf(fabsf(x1 - y1)) << 16);
    }
}

// ---------------------------------------------------------------------------
// Pack conv_w [256][128][5] f32 -> bf16 A-fragments, K tap-major:
// kappa = tap*128 + c.  A-frag for mfma_f32_16x16x32_bf16:
// lane holds A[m = mt*16 + (lane&15)][k = s*32 + (lane>>4)*8 + j], j=0..7.
// Linear halfword index: ((s*16 + mt)*64 + lane)*8 + j,  s = tap*4 + cbi.
// ---------------------------------------------------------------------------
__global__ void pack_w_kernel(const float* __restrict__ w,
                              unsigned short* __restrict__ wp) {
    int tid = blockIdx.x * blockDim.x + threadIdx.x;   // 20480 threads total
    if (tid >= 20 * 16 * 64) return;
    int s    = tid >> 10;
    int mt   = (tid >> 6) & 15;
    int lane = tid & 63;
    int m    = mt * 16 + (lane & 15);
    int kb   = s * 32 + ((lane >> 4) & 3) * 8;
    uint32_t pv[4];
    for (int jj = 0; jj < 4; ++jj) {
        unsigned short lo, hi;
        {
            int kk = kb + 2 * jj;
            int t = kk >> 7, c = kk & 127;
            lo = f2bf(w[(m * C_IN + c) * KTAP + t]);
        }
        {
            int kk = kb + 2 * jj + 1;
            int t = kk >> 7, c = kk & 127;
            hi = f2bf(w[(m * C_IN + c) * KTAP + t]);
        }
        pv[jj] = (uint32_t)lo | ((uint32_t)hi << 16);
    }
    uint4 val; val.x = pv[0]; val.y = pv[1]; val.z = pv[2]; val.w = pv[3];
    *(uint4*)(wp + (size_t)tid * 8) = val;
}

// ---------------------------------------------------------------------------
// Transpose x [B][C][E] f32 -> xT [B][E][C] bf16 (coalesced gathers in GEMM).
// ---------------------------------------------------------------------------
__global__ void transpose_kernel(const float* __restrict__ x,
                                 unsigned short* __restrict__ xT) {
    __shared__ float ld[C_IN][64 + 1];
    int b  = blockIdx.y;
    int e0 = blockIdx.x * 64;
    int t  = threadIdx.x;
    bool full = (e0 + 64 <= E_N);
    for (int pass = 0; pass < 8; ++pass) {
        int c  = pass * 16 + (t >> 4);
        int eo = (t & 15) * 4;
        if (full) {
            const float4 v = *(const float4*)(x + ((size_t)(b * C_IN + c) * E_N + e0 + eo));
            ld[c][eo] = v.x; ld[c][eo + 1] = v.y; ld[c][eo + 2] = v.z; ld[c][eo + 3] = v.w;
        } else {
            for (int i = 0; i < 4; ++i) {
                int e = e0 + eo + i;
                ld[c][eo + i] = (e < E_N) ? x[(size_t)(b * C_IN + c) * E_N + e] : 0.f;
            }
        }
    }
    __syncthreads();
    for (int pass = 0; pass < 4; ++pass) {
        int el = pass * 16 + (t >> 4);
        int c0 = (t & 15) * 8;
        int e  = e0 + el;
        if (e < E_N) {
            uint32_t pk[4];
            for (int i = 0; i < 4; ++i) {
                unsigned short lo = f2bf(ld[c0 + 2 * i][el]);
                unsigned short hi = f2bf(ld[c0 + 2 * i + 1][el]);
                pk[i] = (uint32_t)lo | ((uint32_t)hi << 16);
            }
            uint4 v; v.x = pk[0]; v.y = pk[1]; v.z = pk[2]; v.w = pk[3];
            *(uint4*)(xT + (size_t)(b * E_N + e) * C_IN + c0) = v;
        }
    }
}

// ---------------------------------------------------------------------------
// Fused gather + tap-combine + GEMM, BATCH-MERGED s-loop.
//
// Each block: one 64-edge tile x one batch PAIR (b = 2*blockIdx.y + {0,1}).
// BOTH batches' combined taps staged in LDS (160 KB, 1 block/CU), then ONE
// s-loop where each weight fragment pair feeds 16 MFMAs (4 nt x 2 mt x 2
// batches) -- weight L2 traffic halves vs the per-batch-phase version
// (600 MB -> 300 MB) and each load's latency is covered by 2x the compute.
// Single barrier per block (gather/combine -> barrier -> MFMA/store).
// amdgpu_waves_per_eu(2,2) pins the allocator at 256 VGPR / 2 waves per
// SIMD so the merged accumulators (64 VGPR) + transient w/B regs fit
// without the round-1 spill failure mode.
// ---------------------------------------------------------------------------
__launch_bounds__(512)
__attribute__((amdgpu_waves_per_eu(2, 2)))
__global__ void mesh_gemm(const unsigned short* __restrict__ wp,
                          const unsigned short* __restrict__ xT,
                          const int* __restrict__ ne,
                          const float* __restrict__ bias,
                          float* __restrict__ out) {
    __shared__ uint4 gbuf[2][KTAP][BN][16];   // 163,840 B (XOR-swizzled chunks)

    const int tid  = threadIdx.x;
    const int lane = tid & 63;
    const int wave = tid >> 6;
    const int e0   = blockIdx.x * BN;
    const int b0   = blockIdx.y * 2;
    const int b1   = b0 + 1;

    // gather role: 8 threads/edge, each owns chunks ci and ci+8
    const int col = tid >> 3;
    const int ci  = tid & 7;
    const int sw  = col & 15;
    const int cl  = ci ^ sw;
    const int ch  = (ci + 8) ^ sw;
    int eg = e0 + col; if (eg >= E_N) eg = E_N - 1;

    const int4 nb0 = *(const int4*)(ne + ((size_t)b0 * E_N + eg) * 4);
    const int4 nb1 = *(const int4*)(ne + ((size_t)b1 * E_N + eg) * 4);

    const unsigned short* xb0 = xT + (size_t)b0 * E_N * C_IN;
    const unsigned short* xb1 = xT + (size_t)b1 * E_N * C_IN;

    // MFMA-role constants
    const uint4* wp16 = (const uint4*)wp;
    const int nl = lane & 15;
    const int kq = lane >> 4;

    // hoist bias
    float bvl[2][4];
#pragma unroll
    for (int mt = 0; mt < 2; ++mt)
#pragma unroll
        for (int r = 0; r < 4; ++r)
            bvl[mt][r] = bias[(wave * 2 + mt) * 16 + kq * 4 + r];

    // ---------------- gather phase (both batches, 20 loads in flight) ------
    auto gather10 = [&](const unsigned short* xb, const int4& nb, uint4* g) {
        const uint4* r0 = (const uint4*)(xb + (size_t)eg   * C_IN) + ci;
        const uint4* r1 = (const uint4*)(xb + (size_t)nb.x * C_IN) + ci;
        const uint4* r2 = (const uint4*)(xb + (size_t)nb.y * C_IN) + ci;
        const uint4* r3 = (const uint4*)(xb + (size_t)nb.z * C_IN) + ci;
        const uint4* r4 = (const uint4*)(xb + (size_t)nb.w * C_IN) + ci;
        g[0] = r0[0]; g[1] = r1[0]; g[2] = r2[0]; g[3] = r3[0]; g[4] = r4[0];
        g[5] = r0[8]; g[6] = r1[8]; g[7] = r2[8]; g[8] = r3[8]; g[9] = r4[8];
    };
    auto combineStore = [&](const uint4* g, int bh) {
        uint4 s, d;
        gbuf[bh][0][col][cl] = g[0];
        comb8(g[1], g[3], s, d); gbuf[bh][1][col][cl] = s; gbuf[bh][3][col][cl] = d;
        comb8(g[2], g[4], s, d); gbuf[bh][2][col][cl] = s; gbuf[bh][4][col][cl] = d;
        gbuf[bh][0][col][ch] = g[5];
        comb8(g[6], g[8], s, d); gbuf[bh][1][col][ch] = s; gbuf[bh][3][col][ch] = d;
        comb8(g[7], g[9], s, d); gbuf[bh][2][col][ch] = s; gbuf[bh][4][col][ch] = d;
    };

    {
        uint4 g0[10], g1[10];
        gather10(xb0, nb0, g0);
        gather10(xb1, nb1, g1);
        combineStore(g0, 0);
        combineStore(g1, 1);
    }
    __syncthreads();                       // both batches staged

    // ---------------- merged MFMA phase ----------------
    f32x4 acc[2][2][4];                    // [batch][mt][nt]
#pragma unroll
    for (int bh = 0; bh < 2; ++bh)
#pragma unroll
        for (int mt = 0; mt < 2; ++mt)
#pragma unroll
            for (int nt = 0; nt < 4; ++nt)
                acc[bh][mt][nt] = (f32x4){0.f, 0.f, 0.f, 0.f};

#pragma unroll 4
    for (int s = 0; s < 20; ++s) {
        const int tap = s >> 2, cbi = s & 3;
        uint4 w0 = wp16[(s * 16 + wave * 2 + 0) * 64 + lane];
        uint4 w1 = wp16[(s * 16 + wave * 2 + 1) * 64 + lane];
        bf16x8 af0 = *(bf16x8*)&w0;
        bf16x8 af1 = *(bf16x8*)&w1;
#pragma unroll
        for (int nt = 0; nt < 4; ++nt) {
            const int cidx = ((cbi << 2) + kq) ^ nl;
            uint4 bv0 = gbuf[0][tap][nt * 16 + nl][cidx];
            bf16x8 bf0 = *(bf16x8*)&bv0;
            acc[0][0][nt] = __builtin_amdgcn_mfma_f32_16x16x32_bf16(af0, bf0, acc[0][0][nt], 0, 0, 0);
            acc[0][1][nt] = __builtin_amdgcn_mfma_f32_16x16x32_bf16(af1, bf0, acc[0][1][nt], 0, 0, 0);
            uint4 bv1 = gbuf[1][tap][nt * 16 + nl][cidx];
            bf16x8 bf1 = *(bf16x8*)&bv1;
            acc[1][0][nt] = __builtin_amdgcn_mfma_f32_16x16x32_bf16(af0, bf1, acc[1][0][nt], 0, 0, 0);
            acc[1][1][nt] = __builtin_amdgcn_mfma_f32_16x16x32_bf16(af1, bf1, acc[1][1][nt], 0, 0, 0);
        }
    }

    // ---------------- epilogue: C/D col = lane&15, row = kq*4 + r ----------
#pragma unroll
    for (int bh = 0; bh < 2; ++bh) {
        float* outb = out + (size_t)(b0 + bh) * C_OUT * E_N;
#pragma unroll
        for (int mt = 0; mt < 2; ++mt) {
            const int ob = (wave * 2 + mt) * 16 + kq * 4;
#pragma unroll
            for (int r = 0; r < 4; ++r) {
                const int o = ob + r;
                const float bv = bvl[mt][r];
#pragma unroll
                for (int nt = 0; nt < 4; ++nt) {
                    const int e = e0 + nt * 16 + nl;
                    if (e < E_N)
                        outb[(size_t)o * E_N + e] = acc[bh][mt][nt][r] + bv;
                }
            }
        }
    }
}

// ---------------------------------------------------------------------------
// Fallback (ws too small): direct fp32 compute, slow but correct.
// ---------------------------------------------------------------------------
__global__ void fallback_kernel(const float* __restrict__ x,
                                const int* __restrict__ ne,
                                const float* __restrict__ w,
                                const float* __restrict__ bias,
                                float* __restrict__ out) {
    size_t id = (size_t)blockIdx.x * blockDim.x + threadIdx.x;
    if (id >= (size_t)B_N * C_OUT * E_N) return;
    int e = (int)(id % E_N);
    int o = (int)((id / E_N) % C_OUT);
    int b = (int)(id / ((size_t)E_N * C_OUT));
    const int4 nb = *(const int4*)(ne + ((size_t)b * E_N + e) * 4);
    float acc = bias[o];
    for (int c = 0; c < C_IN; ++c) {
        const float* xb = x + (size_t)(b * C_IN + c) * E_N;
        float s0 = xb[e];
        float x1 = xb[nb.x], x2 = xb[nb.y], x3 = xb[nb.z], x4 = xb[nb.w];
        const float* wo = w + (size_t)(o * C_IN + c) * KTAP;
        acc += wo[0] * s0
             + wo[1] * (x1 + x3)
             + wo[2] * (x2 + x4)
             + wo[3] * fabsf(x1 - x3)
             + wo[4] * fabsf(x2 - x4);
    }
    out[id] = acc;
}

extern "C" void kernel_launch(void* const* d_in, const int* in_sizes, int n_in,
                              void* d_out, int out_size, void* d_ws, size_t ws_size,
                              hipStream_t stream) {
    const float* x      = (const float*)d_in[0];
    const int*   ne_idx = (const int*)d_in[1];
    const float* conv_w = (const float*)d_in[2];
    const float* conv_b = (const float*)d_in[3];
    float* out = (float*)d_out;

    const size_t xT_off = 512 * 1024;
    const size_t need   = xT_off + (size_t)B_N * E_N * C_IN * 2;  // ~31.2 MB

    if (ws_size < need) {
        size_t total = (size_t)B_N * C_OUT * E_N;
        int blocks = (int)((total + 255) / 256);
        fallback_kernel<<<blocks, 256, 0, stream>>>(x, ne_idx, conv_w, conv_b, out);
        return;
    }

    unsigned short* wp = (unsigned short*)d_ws;
    unsigned short* xT = (unsigned short*)((char*)d_ws + xT_off);

    pack_w_kernel<<<80, 256, 0, stream>>>(conv_w, wp);
    dim3 tg((E_N + 63) / 64, B_N);
    transpose_kernel<<<tg, 256, 0, stream>>>(x, xT);
    dim3 gg((E_N + BN - 1) / BN, B_N / 2);
    mesh_gemm<<<gg, 512, 0, stream>>>(wp, xT, ne_idx, conv_b, out);
}